// Round 3
// baseline (102.285 us; speedup 1.0000x reference)
//
#include <hip/hip_runtime.h>
#include <stdint.h>

#define BB 32
#define NN 8000
#define MM 256
#define LL (NN + MM)        // 8256
#define NSAMP 512
#define MAXPOS 128
#define T2 1024
#define CH ((LL + T2 - 1) / T2)   // 9

// forbid fp-contract across this value (match numpy's non-FMA rounding)
__device__ __forceinline__ void opaquef(float& x) { asm volatile("" : "+v"(x)); }

// ---------------- kernel 1: per-(b,l) best-match + classification ----------
// Division-free argmax: compare candidate iou = inter/uni against running best
// (bestI/bestU) via cross-multiplication with a conservative 2^-21 margin.
// |d| > t guarantees the ROUNDED quotients (reference semantics) order the
// same way as the true ratios; the rare ambiguous band falls back to exact
// IEEE division of both, which is bit-identical to the reference compare.
__global__ __launch_bounds__(256) void match_kernel(
    const float* __restrict__ boxes, const float* __restrict__ gt,
    int* __restrict__ packed)
{
    __shared__ float4 s_gt[MM];
    __shared__ float  s_a2[MM];
    const int b = blockIdx.y, tid = threadIdx.x;
    {
        float4 v = ((const float4*)(gt + (size_t)b * MM * 4))[tid];
        s_gt[tid] = v;
        s_a2[tid] = (v.z - v.x) * (v.w - v.y);   // invalid gt (-1,...) -> 0
    }
    __syncthreads();
    const int l = blockIdx.x * 256 + tid;
    if (l >= LL) return;

    float4 bx = (l < NN) ? ((const float4*)(boxes + (size_t)b * NN * 4))[l]
                         : s_gt[l - NN];
    const bool binv = fmaxf(fmaxf(bx.x, bx.y), fmaxf(bx.z, bx.w)) < 0.0f;

    int cls, bidx = 0;
    if (binv) {
        cls = 2;                 // all sim == -1 -> invalid, argmax = 0
    } else {
        // Invalid gt boxes yield inter = 0 -> can never win (reference's -1
        // entries also never win for a valid box, and ties-at-0 keep the
        // first index in both schemes).
        float a1 = (bx.z - bx.x) * (bx.w - bx.y);
        opaquef(a1);
        float bestI = 0.0f, bestU = 1.0f;   // ratio 0
        #pragma unroll 4
        for (int m = 0; m < MM; ++m) {
            float4 g = s_gt[m];
            float ih = fmaxf(fminf(bx.z, g.z) - fmaxf(bx.x, g.x), 0.0f);
            float iw = fmaxf(fminf(bx.w, g.w) - fmaxf(bx.y, g.y), 0.0f);
            float inter = ih * iw;
            opaquef(inter);
            float uni = (a1 + s_a2[m]) - inter;   // numpy op order/rounding
            float p1 = inter * bestU;
            float p2 = bestI * uni;
            float d  = p1 - p2;
            float t  = 4.76837158203125e-07f * fmaxf(p1, p2);  // 2^-21
            bool win = d > t;
            bool amb = (fabsf(d) <= t) && (p1 > 0.0f);
            if (__any(amb)) {                     // ~1e-6 of iterations
                float qn = inter / uni;           // uni >= inter > 0 here
                float qb = bestI / bestU;
                if (amb) win = qn > qb;           // exact rounded compare
            }
            if (win) { bestI = inter; bestU = uni; bidx = m; }
        }
        // exact rounded matched_val for the winner pair (same (inter,uni)
        // the reference divides, so bit-identical)
        float q = bestI / bestU;                  // bestU > 0 always
        // searchsorted([0,.5,.5], right): q>=0 here -> neg(0) or pos(1)
        cls = (q >= 0.5f) ? 1 : 0;
    }
    packed[(size_t)b * LL + l] = cls | (bidx << 2);
}

// ---------------- fast block exclusive scan (1024 thr = 16 waves) ----------
// Returns exclusive prefix of v. After return (and until the next call
// overwrites wt), wt[15] holds the block total. 2 syncthreads.
__device__ __forceinline__ int block_exscan_fast(int v, int* wt, int tid)
{
    const int lane = tid & 63, w = tid >> 6;
    int x = v;
    #pragma unroll
    for (int off = 1; off < 64; off <<= 1) {
        int y = __shfl_up(x, off);
        if (lane >= off) x += y;
    }
    if (lane == 63) wt[w] = x;
    __syncthreads();
    if (tid < 64) {
        int t = (tid < 16) ? wt[tid] : 0;
        #pragma unroll
        for (int off = 1; off < 16; off <<= 1) {
            int y = __shfl_up(t, off);
            if (tid >= off) t += y;
        }
        if (tid < 16) wt[tid] = t;
    }
    __syncthreads();
    return ((w > 0) ? wt[w - 1] : 0) + x - v;
}

// find K-th-largest key among {l : cls[l]==c}; returns threshold key and
// rem = number of ties at the threshold to take (in index order)
__device__ void radix_select(const uint32_t* key, const uint8_t* cls, int c, int K,
                             int* hist, int* sb, int* wt, int tid,
                             uint32_t* thrKey, int* rem)
{
    uint32_t prefix = 0;
    int remaining = K;
    for (int round = 0; round < 4; ++round) {
        const int shift = 24 - 8 * round;
        if (tid < 256) hist[tid] = 0;
        __syncthreads();
        const uint32_t pmask = (round == 0) ? 0u : (0xFFFFFFFFu << (shift + 8));
        for (int l = tid; l < LL; l += T2) {
            if (cls[l] == c) {
                uint32_t k = key[l];
                if ((k & pmask) == prefix) atomicAdd(&hist[(k >> shift) & 255], 1);
            }
        }
        __syncthreads();
        // parallel bin search: suffix sums via reversed exclusive scan
        int h = (tid < 256) ? hist[255 - tid] : 0;
        int above = block_exscan_fast(h, wt, tid);   // sum over bins > (255-tid)
        if (tid < 256) {
            if (above < remaining && above + h >= remaining) {
                sb[2] = 255 - tid;   // unique crossing bin
                sb[3] = above;
            }
        }
        __syncthreads();
        const int bin = sb[2], abv = sb[3];
        remaining -= abv;
        prefix |= ((uint32_t)bin) << shift;
        __syncthreads();   // protect sb reads vs any later writes
    }
    *thrKey = prefix;
    *rem = remaining;
}

__device__ void mark_select(const uint32_t* key, const uint8_t* cls, uint8_t* sel,
                            int c, uint32_t thrKey, int rem, int* wt, int tid)
{
    const int lo = tid * CH, hi = (lo + CH < LL) ? (lo + CH) : LL;
    int nt = 0;
    for (int l = lo; l < hi; ++l)
        if (cls[l] == c && key[l] == thrKey) ++nt;
    int base = block_exscan_fast(nt, wt, tid);
    for (int l = lo; l < hi; ++l) {
        if (cls[l] != c) continue;
        const uint32_t k = key[l];
        if (k > thrKey) sel[l] = 1;
        else if (k == thrKey) { if (base < rem) sel[l] = 1; ++base; }
    }
}

// ---------------- kernel 2: per-batch sampling + gather ----------------
__global__ __launch_bounds__(T2) void sample_kernel(
    const float* __restrict__ boxes, const float* __restrict__ gt,
    const int* __restrict__ gtc, const float* __restrict__ rnd,
    const int* __restrict__ packed, float* __restrict__ out)
{
    __shared__ uint32_t s_key[LL];
    __shared__ uint8_t  s_cls[LL];
    __shared__ uint8_t  s_sel[LL];
    __shared__ int s_warp[16];
    __shared__ int s_hist[256];
    __shared__ int s_idx[NSAMP];
    __shared__ int s_b[6];
    const int b = blockIdx.x, tid = threadIdx.x;
    const int lane = tid & 63;

    if (tid < 6) s_b[tid] = 0;
    __syncthreads();

    int locP = 0, locN = 0;
    for (int l = tid; l < LL; l += T2) {
        s_key[l] = __float_as_uint(rnd[(size_t)b * LL + l]);
        int p = packed[(size_t)b * LL + l];
        uint8_t c = (uint8_t)(p & 3);
        s_cls[l] = c;
        s_sel[l] = 0;
        locP += (c == 1);
        locN += (c == 0);
    }
    #pragma unroll
    for (int off = 32; off; off >>= 1) {
        locP += __shfl_xor(locP, off);
        locN += __shfl_xor(locN, off);
    }
    if (lane == 0) { atomicAdd(&s_b[0], locP); atomicAdd(&s_b[1], locN); }
    __syncthreads();
    const int P = s_b[0], Nn = s_b[1];

    // --- positives: top MAXPOS by rand (stable ties) ---
    const int posK = (P < MAXPOS) ? P : MAXPOS;
    if (P > MAXPOS) {
        uint32_t tk; int rem;
        radix_select(s_key, s_cls, 1, MAXPOS, s_hist, s_b, s_warp, tid, &tk, &rem);
        mark_select(s_key, s_cls, s_sel, 1, tk, rem, s_warp, tid);
    } else {
        for (int l = tid; l < LL; l += T2) if (s_cls[l] == 1) s_sel[l] = 1;
    }
    __syncthreads();

    // --- negatives: top (512-posK) by rand ---
    const int negK = NSAMP - posK;
    if (Nn > negK) {
        uint32_t tk; int rem;
        radix_select(s_key, s_cls, 0, negK, s_hist, s_b, s_warp, tid, &tk, &rem);
        mark_select(s_key, s_cls, s_sel, 0, tk, rem, s_warp, tid);
    } else {
        for (int l = tid; l < LL; l += T2) if (s_cls[l] == 0) s_sel[l] = 1;
    }
    __syncthreads();

    // --- stable compaction: selected ascending, then unselected ascending ---
    const int lo = tid * CH, hi = (lo + CH < LL) ? (lo + CH) : LL;
    int cs = 0;
    for (int l = lo; l < hi; ++l) cs += s_sel[l];
    int base = block_exscan_fast(cs, s_warp, tid);
    const int S = s_warp[16 - 1];            // block total (valid until next scan)
    for (int l = lo; l < hi; ++l)
        if (s_sel[l]) { if (base < NSAMP) s_idx[base] = l; ++base; }

    int cu = 0;
    for (int l = lo; l < hi; ++l) cu += (s_sel[l] == 0);
    __syncthreads();                          // protect s_warp[15] reads above
    int base2 = block_exscan_fast(cu, s_warp, tid) + S;
    for (int l = lo; l < hi; ++l)
        if (!s_sel[l]) { if (base2 < NSAMP) s_idx[base2] = l; ++base2; }
    __syncthreads();

    // --- gather + write all 4 outputs (ints written as float values) ---
    if (tid < NSAMP) {
        const int l = s_idx[tid];
        float4 bx = (l < NN) ? ((const float4*)(boxes + (size_t)b * NN * 4))[l]
                             : ((const float4*)(gt + (size_t)b * MM * 4))[l - NN];
        const int p = packed[(size_t)b * LL + l];
        const int c = p & 3, mi = p >> 2;
        const bool bg = (c != 1);          // background = matched_val < 0.5
        float4 gb = make_float4(0.f, 0.f, 0.f, 0.f);
        int cl = 0, si = -1;
        if (!bg) {
            gb = ((const float4*)(gt + (size_t)b * MM * 4))[mi];
            cl = gtc[(size_t)b * MM + mi];
            si = mi;
        }
        const size_t rk = (size_t)b * NSAMP + tid;
        ((float4*)out)[rk] = bx;                                   // rois
        ((float4*)(out + (size_t)BB * NSAMP * 4))[rk] = gb;        // sampled_gt_boxes
        out[(size_t)2 * BB * NSAMP * 4 + rk] = (float)cl;          // sampled_gt_classes
        out[(size_t)2 * BB * NSAMP * 4 + (size_t)BB * NSAMP + rk] = (float)si; // indices
    }
}

extern "C" void kernel_launch(void* const* d_in, const int* in_sizes, int n_in,
                              void* d_out, int out_size, void* d_ws, size_t ws_size,
                              hipStream_t stream)
{
    const float* boxes = (const float*)d_in[0];   // [32,8000,4] f32
    const float* gt    = (const float*)d_in[1];   // [32,256,4]  f32
    const int*   gtc   = (const int*)  d_in[2];   // [32,256]    i32
    const float* rnd   = (const float*)d_in[3];   // [32,8256]   f32
    float* out = (float*)d_out;
    int* packed = (int*)d_ws;                     // BB*LL ints = 1.06 MB

    dim3 g1((LL + 255) / 256, BB);
    match_kernel<<<g1, 256, 0, stream>>>(boxes, gt, packed);
    sample_kernel<<<BB, T2, 0, stream>>>(boxes, gt, gtc, rnd, packed, out);
}

// Round 4
// 86.412 us; speedup vs baseline: 1.1837x; 1.1837x over previous
//
#include <hip/hip_runtime.h>
#include <stdint.h>

#define BB 32
#define NN 8000
#define MM 256
#define LL (NN + MM)        // 8256
#define NSAMP 512
#define MAXPOS 128
#define T2 1024
#define CH ((LL + T2 - 1) / T2)   // 9
#define SPLIT 4
#define MSUB (MM / SPLIT)   // 64
#define MARGIN 9.5367431640625e-07f   // 2^-20: covers uni/div/product rounding slop

// forbid fp-contract across this value (match numpy's non-FMA rounding)
__device__ __forceinline__ void opaquef(float& x) { asm volatile("" : "+v"(x)); }

// ---------------- kernel 1: per-(b,l,split) best-match over 64 gts ---------
// Division-free: with s = fl(a1+a2), exact identity i/(s-i) > j/(t-j) <=>
// i*t > j*s. Margin 2^-20 absorbs all rounding (products 2*2^-24, reference's
// uni = fl(s-i) 2^-24, division 2^-24); outside the margin the ROUNDED
// quotients are strictly ordered; inside -> redo this thread's sub-loop with
// exact IEEE divisions (bit-identical to reference compare).
__global__ __launch_bounds__(256) void match_split_kernel(
    const float* __restrict__ boxes, const float* __restrict__ gt,
    uint8_t* __restrict__ pidx)
{
    __shared__ float4 s_gt[MSUB];
    __shared__ float  s_a2[MSUB];
    const int b = blockIdx.y, sp = blockIdx.z, tid = threadIdx.x;
    if (tid < MSUB) {
        float4 v = ((const float4*)(gt + ((size_t)b * MM + sp * MSUB) * 4))[tid];
        s_gt[tid] = v;
        s_a2[tid] = (v.z - v.x) * (v.w - v.y);   // invalid gt (-1,...) -> 0
    }
    __syncthreads();
    const int l = blockIdx.x * 256 + tid;
    if (l >= LL) return;

    float4 bx = (l < NN) ? ((const float4*)(boxes + (size_t)b * NN * 4))[l]
                         : ((const float4*)(gt + (size_t)b * MM * 4))[l - NN];
    int lbidx = 0;
    if (!(fmaxf(fmaxf(bx.x, bx.y), fmaxf(bx.z, bx.w)) < 0.0f)) {
        float a1 = (bx.z - bx.x) * (bx.w - bx.y);
        opaquef(a1);
        // two independent chains (even/odd m) for ILP
        float bI0 = 0.0f, bS0 = 1.0f, bI1 = 0.0f, bS1 = 1.0f;
        int bi0 = 0, bi1 = 1;
        bool redo = false;
        #pragma unroll 8
        for (int m = 0; m < MSUB; m += 2) {
            {
                float4 g = s_gt[m];
                float ih = fmaxf(fminf(bx.z, g.z) - fmaxf(bx.x, g.x), 0.0f);
                float iw = fmaxf(fminf(bx.w, g.w) - fmaxf(bx.y, g.y), 0.0f);
                float inter = ih * iw; opaquef(inter);
                float s  = a1 + s_a2[m];
                float p1 = inter * bS0, p2 = bI0 * s;
                float d  = p1 - p2, t = MARGIN * fmaxf(p1, p2);
                redo = redo || (fabsf(d) <= t && inter > 0.0f);
                if (d > t) { bI0 = inter; bS0 = s; bi0 = m; }
            }
            {
                float4 g = s_gt[m + 1];
                float ih = fmaxf(fminf(bx.z, g.z) - fmaxf(bx.x, g.x), 0.0f);
                float iw = fmaxf(fminf(bx.w, g.w) - fmaxf(bx.y, g.y), 0.0f);
                float inter = ih * iw; opaquef(inter);
                float s  = a1 + s_a2[m + 1];
                float p1 = inter * bS1, p2 = bI1 * s;
                float d  = p1 - p2, t = MARGIN * fmaxf(p1, p2);
                redo = redo || (fabsf(d) <= t && inter > 0.0f);
                if (d > t) { bI1 = inter; bS1 = s; bi1 = m + 1; }
            }
        }
        // merge chains: odd wins only if STRICTLY greater (rounded); equality
        // must fall back (true first-argmax may be the odd, lower index)
        {
            float p1 = bI1 * bS0, p2 = bI0 * bS1;
            float d  = p1 - p2, t = MARGIN * fmaxf(p1, p2);
            if (d > t) { bi0 = bi1; }
            else if (fabsf(d) <= t && bI1 > 0.0f) redo = true;
        }
        lbidx = bi0;
        if (redo) {   // rare: exact reference semantics, serial with IEEE div
            float qb = -1.0f; int bi = 0;
            for (int m = 0; m < MSUB; ++m) {
                float4 g = s_gt[m];
                float ih = fmaxf(fminf(bx.z, g.z) - fmaxf(bx.x, g.x), 0.0f);
                float iw = fmaxf(fminf(bx.w, g.w) - fmaxf(bx.y, g.y), 0.0f);
                float inter = ih * iw; opaquef(inter);
                float uni = (a1 + s_a2[m]) - inter;
                float q = (uni > 0.0f) ? (inter / uni) : 0.0f;
                if (q > qb) { qb = q; bi = m; }
            }
            lbidx = bi;
        }
    }
    pidx[((size_t)b * LL + l) * SPLIT + sp] = (uint8_t)lbidx;
}

// ---------------- kernel 1b: merge 4 split winners, exact rounded q --------
__global__ __launch_bounds__(256) void merge_kernel(
    const float* __restrict__ boxes, const float* __restrict__ gt,
    const uint8_t* __restrict__ pidx, uint16_t* __restrict__ packed)
{
    const int b = blockIdx.y;
    const int l = blockIdx.x * 256 + threadIdx.x;
    if (l >= LL) return;
    float4 bx = (l < NN) ? ((const float4*)(boxes + (size_t)b * NN * 4))[l]
                         : ((const float4*)(gt + (size_t)b * MM * 4))[l - NN];
    int cls, bidx = 0;
    if (fmaxf(fmaxf(bx.x, bx.y), fmaxf(bx.z, bx.w)) < 0.0f) {
        cls = 2;   // all sim == -1 -> invalid, argmax = 0
    } else {
        float a1 = (bx.z - bx.x) * (bx.w - bx.y);
        opaquef(a1);
        float qb = -1.0f;
        const uint32_t pv = *(const uint32_t*)&pidx[((size_t)b * LL + l) * SPLIT];
        #pragma unroll
        for (int sp = 0; sp < SPLIT; ++sp) {
            const int m = sp * MSUB + (int)((pv >> (8 * sp)) & 0xFFu);
            float4 g = ((const float4*)(gt + (size_t)b * MM * 4))[m];
            float a2 = (g.z - g.x) * (g.w - g.y);
            float ih = fmaxf(fminf(bx.z, g.z) - fmaxf(bx.x, g.x), 0.0f);
            float iw = fmaxf(fminf(bx.w, g.w) - fmaxf(bx.y, g.y), 0.0f);
            float inter = ih * iw; opaquef(inter);
            float uni = (a1 + a2) - inter;        // numpy op order/rounding
            float q = (uni > 0.0f) ? (inter / uni) : 0.0f;   // exact reference
            if (q > qb) { qb = q; bidx = m; }     // split order = index order
        }
        // searchsorted([0,.5,.5], right): q>=0 -> neg(0) or pos(1)
        cls = (qb >= 0.5f) ? 1 : 0;
    }
    packed[(size_t)b * LL + l] = (uint16_t)(cls | (bidx << 2));
}

// ---------------- fast block exclusive scan (1024 thr = 16 waves) ----------
__device__ __forceinline__ int block_exscan_fast(int v, int* wt, int tid)
{
    const int lane = tid & 63, w = tid >> 6;
    int x = v;
    #pragma unroll
    for (int off = 1; off < 64; off <<= 1) {
        int y = __shfl_up(x, off);
        if (lane >= off) x += y;
    }
    if (lane == 63) wt[w] = x;
    __syncthreads();
    if (tid < 64) {
        int t = (tid < 16) ? wt[tid] : 0;
        #pragma unroll
        for (int off = 1; off < 16; off <<= 1) {
            int y = __shfl_up(t, off);
            if (tid >= off) t += y;
        }
        if (tid < 16) wt[tid] = t;
    }
    __syncthreads();
    return ((w > 0) ? wt[w - 1] : 0) + x - v;
}

// find K-th-largest key among {l : cls[l]==c}; returns threshold key and
// rem = number of ties at the threshold to take (in index order)
__device__ void radix_select(const uint32_t* key, const uint8_t* cls, int c, int K,
                             int* hist, int* sb, int* wt, int tid,
                             uint32_t* thrKey, int* rem)
{
    uint32_t prefix = 0;
    int remaining = K;
    for (int round = 0; round < 4; ++round) {
        const int shift = 24 - 8 * round;
        if (tid < 256) hist[tid] = 0;
        __syncthreads();
        const uint32_t pmask = (round == 0) ? 0u : (0xFFFFFFFFu << (shift + 8));
        for (int l = tid; l < LL; l += T2) {
            if (cls[l] == c) {
                uint32_t k = key[l];
                if ((k & pmask) == prefix) atomicAdd(&hist[(k >> shift) & 255], 1);
            }
        }
        __syncthreads();
        int h = (tid < 256) ? hist[255 - tid] : 0;
        int above = block_exscan_fast(h, wt, tid);
        if (tid < 256) {
            if (above < remaining && above + h >= remaining) {
                sb[2] = 255 - tid;
                sb[3] = above;
            }
        }
        __syncthreads();
        const int bin = sb[2], abv = sb[3];
        remaining -= abv;
        prefix |= ((uint32_t)bin) << shift;
        __syncthreads();
    }
    *thrKey = prefix;
    *rem = remaining;
}

__device__ void mark_select(const uint32_t* key, const uint8_t* cls, uint8_t* sel,
                            int c, uint32_t thrKey, int rem, int* wt, int tid)
{
    const int lo = tid * CH, hi = (lo + CH < LL) ? (lo + CH) : LL;
    int nt = 0;
    for (int l = lo; l < hi; ++l)
        if (cls[l] == c && key[l] == thrKey) ++nt;
    int base = block_exscan_fast(nt, wt, tid);
    for (int l = lo; l < hi; ++l) {
        if (cls[l] != c) continue;
        const uint32_t k = key[l];
        if (k > thrKey) sel[l] = 1;
        else if (k == thrKey) { if (base < rem) sel[l] = 1; ++base; }
    }
}

// ---------------- kernel 2: per-batch sampling + gather ----------------
__global__ __launch_bounds__(T2) void sample_kernel(
    const float* __restrict__ boxes, const float* __restrict__ gt,
    const int* __restrict__ gtc, const float* __restrict__ rnd,
    const uint16_t* __restrict__ packed, float* __restrict__ out)
{
    __shared__ uint32_t s_key[LL];
    __shared__ uint8_t  s_cls[LL];
    __shared__ uint8_t  s_sel[LL];
    __shared__ int s_warp[16];
    __shared__ int s_hist[256];
    __shared__ int s_idx[NSAMP];
    __shared__ int s_b[6];
    const int b = blockIdx.x, tid = threadIdx.x;
    const int lane = tid & 63;

    if (tid < 6) s_b[tid] = 0;
    __syncthreads();

    int locP = 0, locN = 0;
    for (int l = tid; l < LL; l += T2) {
        s_key[l] = __float_as_uint(rnd[(size_t)b * LL + l]);
        int p = packed[(size_t)b * LL + l];
        uint8_t c = (uint8_t)(p & 3);
        s_cls[l] = c;
        s_sel[l] = 0;
        locP += (c == 1);
        locN += (c == 0);
    }
    #pragma unroll
    for (int off = 32; off; off >>= 1) {
        locP += __shfl_xor(locP, off);
        locN += __shfl_xor(locN, off);
    }
    if (lane == 0) { atomicAdd(&s_b[0], locP); atomicAdd(&s_b[1], locN); }
    __syncthreads();
    const int P = s_b[0], Nn = s_b[1];

    const int posK = (P < MAXPOS) ? P : MAXPOS;
    if (P > MAXPOS) {
        uint32_t tk; int rem;
        radix_select(s_key, s_cls, 1, MAXPOS, s_hist, s_b, s_warp, tid, &tk, &rem);
        mark_select(s_key, s_cls, s_sel, 1, tk, rem, s_warp, tid);
    } else {
        for (int l = tid; l < LL; l += T2) if (s_cls[l] == 1) s_sel[l] = 1;
    }
    __syncthreads();

    const int negK = NSAMP - posK;
    if (Nn > negK) {
        uint32_t tk; int rem;
        radix_select(s_key, s_cls, 0, negK, s_hist, s_b, s_warp, tid, &tk, &rem);
        mark_select(s_key, s_cls, s_sel, 0, tk, rem, s_warp, tid);
    } else {
        for (int l = tid; l < LL; l += T2) if (s_cls[l] == 0) s_sel[l] = 1;
    }
    __syncthreads();

    const int lo = tid * CH, hi = (lo + CH < LL) ? (lo + CH) : LL;
    int cs = 0;
    for (int l = lo; l < hi; ++l) cs += s_sel[l];
    int base = block_exscan_fast(cs, s_warp, tid);
    const int S = s_warp[15];
    for (int l = lo; l < hi; ++l)
        if (s_sel[l]) { if (base < NSAMP) s_idx[base] = l; ++base; }

    int cu = 0;
    for (int l = lo; l < hi; ++l) cu += (s_sel[l] == 0);
    __syncthreads();
    int base2 = block_exscan_fast(cu, s_warp, tid) + S;
    for (int l = lo; l < hi; ++l)
        if (!s_sel[l]) { if (base2 < NSAMP) s_idx[base2] = l; ++base2; }
    __syncthreads();

    if (tid < NSAMP) {
        const int l = s_idx[tid];
        float4 bx = (l < NN) ? ((const float4*)(boxes + (size_t)b * NN * 4))[l]
                             : ((const float4*)(gt + (size_t)b * MM * 4))[l - NN];
        const int p = packed[(size_t)b * LL + l];
        const int c = p & 3, mi = p >> 2;
        const bool bg = (c != 1);
        float4 gb = make_float4(0.f, 0.f, 0.f, 0.f);
        int cl = 0, si = -1;
        if (!bg) {
            gb = ((const float4*)(gt + (size_t)b * MM * 4))[mi];
            cl = gtc[(size_t)b * MM + mi];
            si = mi;
        }
        const size_t rk = (size_t)b * NSAMP + tid;
        ((float4*)out)[rk] = bx;
        ((float4*)(out + (size_t)BB * NSAMP * 4))[rk] = gb;
        out[(size_t)2 * BB * NSAMP * 4 + rk] = (float)cl;
        out[(size_t)2 * BB * NSAMP * 4 + (size_t)BB * NSAMP + rk] = (float)si;
    }
}

extern "C" void kernel_launch(void* const* d_in, const int* in_sizes, int n_in,
                              void* d_out, int out_size, void* d_ws, size_t ws_size,
                              hipStream_t stream)
{
    const float* boxes = (const float*)d_in[0];   // [32,8000,4] f32
    const float* gt    = (const float*)d_in[1];   // [32,256,4]  f32
    const int*   gtc   = (const int*)  d_in[2];   // [32,256]    i32
    const float* rnd   = (const float*)d_in[3];   // [32,8256]   f32
    float* out = (float*)d_out;
    uint8_t*  pidx   = (uint8_t*)d_ws;                                  // 1.06 MB
    uint16_t* packed = (uint16_t*)((char*)d_ws + (size_t)BB * LL * SPLIT); // 0.53 MB

    dim3 g1((LL + 255) / 256, BB, SPLIT);
    match_split_kernel<<<g1, 256, 0, stream>>>(boxes, gt, pidx);
    dim3 g2((LL + 255) / 256, BB);
    merge_kernel<<<g2, 256, 0, stream>>>(boxes, gt, pidx, packed);
    sample_kernel<<<BB, T2, 0, stream>>>(boxes, gt, gtc, rnd, packed, out);
}

// Round 5
// 73.327 us; speedup vs baseline: 1.3949x; 1.1785x over previous
//
#include <hip/hip_runtime.h>
#include <stdint.h>

#define BB 32
#define NN 8000
#define MM 256
#define LL (NN + MM)        // 8256
#define NSAMP 512
#define MAXPOS 128
#define T2 1024
#define CH ((LL + T2 - 1) / T2)   // 9
#define SPLIT 4
#define MSUB (MM / SPLIT)   // 64
#define MARGIN 1.9073486328125e-06f   // 2^-19, >=4x combined rounding bound

// forbid fp-contract across this value (match numpy rounding); NON-volatile so
// the scheduler can still reorder across iterations.
__device__ __forceinline__ void opaquef(float& x) { asm("" : "+v"(x)); }

// ---------------- kernel 1: per-(b,l,split) best-match over 64 gts ---------
// Division-free: with s = fl(a1+a2), exact identity i/(s-i) > j/(t-j) <=>
// i*t > j*s (denominators positive whenever i,j>0). Decision rule on
// d = p1-p2, t = 2^-19*max(p1,p2): d > t -> guaranteed rounded-quotient win;
// |d| < 2t -> ambiguous, set redo (covers the d==t boundary and all exact
// ties; self-excludes the p1==p2==0 case); else guaranteed lose. redo threads
// rerun serially with exact IEEE divisions (bit-identical to reference).
__global__ __launch_bounds__(256) void match_split_kernel(
    const float* __restrict__ boxes, const float* __restrict__ gt,
    uint8_t* __restrict__ pidx)
{
    __shared__ float4 s_gt[MSUB];
    __shared__ float  s_a2[MSUB];
    const int b = blockIdx.y, sp = blockIdx.z, tid = threadIdx.x;
    if (tid < MSUB) {
        float4 v = ((const float4*)(gt + ((size_t)b * MM + sp * MSUB) * 4))[tid];
        s_gt[tid] = v;
        s_a2[tid] = (v.z - v.x) * (v.w - v.y);   // invalid gt (-1,...) -> 0
    }
    __syncthreads();
    const int l = blockIdx.x * 256 + tid;
    if (l >= LL) return;

    float4 bx = (l < NN) ? ((const float4*)(boxes + (size_t)b * NN * 4))[l]
                         : ((const float4*)(gt + (size_t)b * MM * 4))[l - NN];
    int lbidx = 0;
    if (!(fmaxf(fmaxf(bx.x, bx.y), fmaxf(bx.z, bx.w)) < 0.0f)) {
        float a1 = (bx.z - bx.x) * (bx.w - bx.y);
        opaquef(a1);
        // 4 independent chains (m%4) for ILP; branchless updates
        float bI0 = 0.f, bI1 = 0.f, bI2 = 0.f, bI3 = 0.f;
        float bS0 = 1.f, bS1 = 1.f, bS2 = 1.f, bS3 = 1.f;
        int bi0 = 0, bi1 = 1, bi2 = 2, bi3 = 3;
        bool redo = false;
        #pragma unroll 4
        for (int m = 0; m < MSUB; m += 4) {
            #define CHAIN_STEP(K, BI, BS, BIX)                                   \
            {                                                                    \
                float4 g = s_gt[m + K];                                          \
                float ih = fmaxf(fminf(bx.z, g.z) - fmaxf(bx.x, g.x), 0.0f);     \
                float iw = fmaxf(fminf(bx.w, g.w) - fmaxf(bx.y, g.y), 0.0f);     \
                float inter = ih * iw; opaquef(inter);                           \
                float s  = a1 + s_a2[m + K];                                     \
                float p1 = inter * BS, p2 = BI * s;                              \
                float d  = p1 - p2;                                              \
                float t  = MARGIN * fmaxf(p1, p2);                               \
                redo |= (fabsf(d) < t + t);                                      \
                if (d > t) { BI = inter; BS = s; BIX = m + K; }                  \
            }
            CHAIN_STEP(0, bI0, bS0, bi0)
            CHAIN_STEP(1, bI1, bS1, bi1)
            CHAIN_STEP(2, bI2, bS2, bi2)
            CHAIN_STEP(3, bI3, bS3, bi3)
            #undef CHAIN_STEP
        }
        // merge chains sequentially; strict-win-with-margin adopts, any
        // closeness sets redo (exact ties always land inside the 2t band)
        float bbI = bI0, bbS = bS0; int bbi = bi0;
        #define CHAIN_MERGE(BI, BS, BIX)                                         \
        {                                                                        \
            float p1 = BI * bbS, p2 = bbI * BS;                                  \
            float d  = p1 - p2;                                                  \
            float t  = MARGIN * fmaxf(p1, p2);                                   \
            redo |= (fabsf(d) < t + t);                                          \
            if (d > t) { bbI = BI; bbS = BS; bbi = BIX; }                        \
        }
        CHAIN_MERGE(bI1, bS1, bi1)
        CHAIN_MERGE(bI2, bS2, bi2)
        CHAIN_MERGE(bI3, bS3, bi3)
        #undef CHAIN_MERGE
        lbidx = bbi;
        if (redo) {   // rare: exact reference semantics, serial IEEE div
            float qb = -1.0f; int bi = 0;
            for (int m = 0; m < MSUB; ++m) {
                float4 g = s_gt[m];
                float ih = fmaxf(fminf(bx.z, g.z) - fmaxf(bx.x, g.x), 0.0f);
                float iw = fmaxf(fminf(bx.w, g.w) - fmaxf(bx.y, g.y), 0.0f);
                float inter = ih * iw; opaquef(inter);
                float uni = (a1 + s_a2[m]) - inter;
                float q = (uni > 0.0f) ? (inter / uni) : 0.0f;
                if (q > qb) { qb = q; bi = m; }
            }
            lbidx = bi;
        }
    }
    pidx[((size_t)b * LL + l) * SPLIT + sp] = (uint8_t)lbidx;
}

// ---------------- kernel 1b: merge 4 split winners, exact rounded q --------
__global__ __launch_bounds__(256) void merge_kernel(
    const float* __restrict__ boxes, const float* __restrict__ gt,
    const uint8_t* __restrict__ pidx, uint16_t* __restrict__ packed)
{
    const int b = blockIdx.y;
    const int l = blockIdx.x * 256 + threadIdx.x;
    if (l >= LL) return;
    float4 bx = (l < NN) ? ((const float4*)(boxes + (size_t)b * NN * 4))[l]
                         : ((const float4*)(gt + (size_t)b * MM * 4))[l - NN];
    int cls, bidx = 0;
    if (fmaxf(fmaxf(bx.x, bx.y), fmaxf(bx.z, bx.w)) < 0.0f) {
        cls = 2;   // all sim == -1 -> invalid, argmax = 0
    } else {
        float a1 = (bx.z - bx.x) * (bx.w - bx.y);
        opaquef(a1);
        float qb = -1.0f;
        const uint32_t pv = *(const uint32_t*)&pidx[((size_t)b * LL + l) * SPLIT];
        #pragma unroll
        for (int sp = 0; sp < SPLIT; ++sp) {
            const int m = sp * MSUB + (int)((pv >> (8 * sp)) & 0xFFu);
            float4 g = ((const float4*)(gt + (size_t)b * MM * 4))[m];
            float a2 = (g.z - g.x) * (g.w - g.y); opaquef(a2);
            float ih = fmaxf(fminf(bx.z, g.z) - fmaxf(bx.x, g.x), 0.0f);
            float iw = fmaxf(fminf(bx.w, g.w) - fmaxf(bx.y, g.y), 0.0f);
            float inter = ih * iw; opaquef(inter);
            float uni = (a1 + a2) - inter;        // numpy op order/rounding
            float q = (uni > 0.0f) ? (inter / uni) : 0.0f;   // exact reference
            if (q > qb) { qb = q; bidx = m; }     // split order = index order
        }
        cls = (qb >= 0.5f) ? 1 : 0;
    }
    packed[(size_t)b * LL + l] = (uint16_t)(cls | (bidx << 2));
}

// ---------------- scans ----------------
// Full-block (16-wave) exclusive scan; wt[15] holds block total afterwards.
__device__ __forceinline__ int block_exscan_fast(int v, int* wt, int tid)
{
    const int lane = tid & 63, w = tid >> 6;
    int x = v;
    #pragma unroll
    for (int off = 1; off < 64; off <<= 1) {
        int y = __shfl_up(x, off);
        if (lane >= off) x += y;
    }
    if (lane == 63) wt[w] = x;
    __syncthreads();
    if (tid < 64) {
        int t = (tid < 16) ? wt[tid] : 0;
        #pragma unroll
        for (int off = 1; off < 16; off <<= 1) {
            int y = __shfl_up(t, off);
            if (tid >= off) t += y;
        }
        if (tid < 16) wt[tid] = t;
    }
    __syncthreads();
    return ((w > 0) ? wt[w - 1] : 0) + x - v;
}

// Segmented exclusive scan: independent segments of 4 waves (256 threads).
__device__ __forceinline__ int block_exscan_seg4(int v, int* wt, int tid)
{
    const int lane = tid & 63, w = tid >> 6;
    int x = v;
    #pragma unroll
    for (int off = 1; off < 64; off <<= 1) {
        int y = __shfl_up(x, off);
        if (lane >= off) x += y;
    }
    if (lane == 63) wt[w] = x;
    __syncthreads();
    if (tid < 16) {
        int t = wt[tid];
        #pragma unroll
        for (int off = 1; off < 4; off <<= 1) {
            int y = __shfl_up(t, off);
            if ((tid & 3) >= off) t += y;
        }
        wt[tid] = t;   // inclusive scan within each 4-wave group
    }
    __syncthreads();
    return (((w & 3) > 0) ? wt[w - 1] : 0) + x - v;
}

// ---------------- kernel 2: per-batch sampling + gather ----------------
// s_pk bit layout: [1:0] cls, [9:2] matched gt idx, [15] sel flag
__global__ __launch_bounds__(T2) void sample_kernel(
    const float* __restrict__ boxes, const float* __restrict__ gt,
    const int* __restrict__ gtc, const float* __restrict__ rnd,
    const uint16_t* __restrict__ packed, float* __restrict__ out)
{
    __shared__ uint32_t s_key[LL];     // 33024 B
    __shared__ uint16_t s_pk[LL];      // 16512 B
    __shared__ int s_hist[512];        // 2048 B
    __shared__ int s_warp[16];
    __shared__ int s_idx[NSAMP];       // 2048 B
    __shared__ int s_sb[8];
    const int b = blockIdx.x, tid = threadIdx.x, lane = tid & 63;

    if (tid == 0) s_sb[0] = 0;
    __syncthreads();

    // load + packed class counts (neg low16 | pos high16)
    int loc = 0;
    for (int l = tid; l < LL; l += T2) {
        s_key[l] = __float_as_uint(rnd[(size_t)b * LL + l]);
        uint16_t p = packed[(size_t)b * LL + l];
        s_pk[l] = p;
        int c = p & 3;
        loc += (c == 0) ? 1 : ((c == 1) ? 0x10000 : 0);
    }
    #pragma unroll
    for (int off = 32; off; off >>= 1) loc += __shfl_xor(loc, off);
    if (lane == 0) atomicAdd(&s_sb[0], loc);
    __syncthreads();
    const int Nn = s_sb[0] & 0xFFFF, P = s_sb[0] >> 16;

    const int posK = (P < MAXPOS) ? P : MAXPOS;
    const int negK = NSAMP - posK;
    const bool negRad = (Nn > negK);
    const bool posRad = (P > MAXPOS);

    // --- fused dual-class radix select (4 rounds over 8-bit digits) ---
    uint32_t prefix0 = 0, prefix1 = 0;
    int rem0 = negK, rem1 = MAXPOS;
    if (negRad || posRad) {
        for (int round = 0; round < 4; ++round) {
            const int shift = 24 - 8 * round;
            if (tid < 512) s_hist[tid] = 0;
            __syncthreads();
            const uint32_t pmask = (round == 0) ? 0u : (0xFFFFFFFFu << (shift + 8));
            for (int l = tid; l < LL; l += T2) {
                const uint32_t k = s_key[l];
                const int c = s_pk[l] & 3;
                bool doit = (c == 0) ? (negRad && ((k & pmask) == prefix0))
                          : (c == 1) ? (posRad && ((k & pmask) == prefix1))
                          : false;
                if (doit) atomicAdd(&s_hist[(c << 8) | ((k >> shift) & 255)], 1);
            }
            __syncthreads();
            // reversed scan within each class segment (suffix sums)
            int h = 0;
            if (tid < 512) h = s_hist[(tid & 0x100) | (255 - (tid & 255))];
            const int above = block_exscan_seg4(h, s_warp, tid);
            if (tid < 512) {
                const int c = tid >> 8;
                const int rem = c ? rem1 : rem0;
                const bool act = c ? posRad : negRad;
                if (act && above < rem && above + h >= rem) {
                    s_sb[4 + c * 2] = 255 - (tid & 255);   // crossing bin
                    s_sb[5 + c * 2] = above;               // strictly-above count
                }
            }
            __syncthreads();
            if (negRad) { prefix0 |= ((uint32_t)s_sb[4]) << shift; rem0 -= s_sb[5]; }
            if (posRad) { prefix1 |= ((uint32_t)s_sb[6]) << shift; rem1 -= s_sb[7]; }
            __syncthreads();
        }
    }
    // unify trivial classes: thr=0, rem=LL selects the whole class
    const uint32_t thr0 = negRad ? prefix0 : 0u;  const int r0 = negRad ? rem0 : LL;
    const uint32_t thr1 = posRad ? prefix1 : 0u;  const int r1 = posRad ? rem1 : LL;

    // --- fused mark pass (tie counts packed: neg low16 | pos high16) ---
    const int lo = tid * CH, hi = (lo + CH < LL) ? (lo + CH) : LL;
    int nt = 0;
    for (int l = lo; l < hi; ++l) {
        const int c = s_pk[l] & 3;
        const uint32_t k = s_key[l];
        if (c == 0) { if (k == thr0) nt += 1; }
        else if (c == 1) { if (k == thr1) nt += 0x10000; }
    }
    const int basep = block_exscan_fast(nt, s_warp, tid);
    int base0 = basep & 0xFFFF, base1 = basep >> 16;
    for (int l = lo; l < hi; ++l) {
        const int c = s_pk[l] & 3;
        if (c > 1) continue;
        const uint32_t k = s_key[l];
        const uint32_t thr = c ? thr1 : thr0;
        bool sel = (k > thr);
        if (k == thr) {
            if (c == 0) { sel = (base0 < r0); ++base0; }
            else        { sel = (base1 < r1); ++base1; }
        }
        if (sel) s_pk[l] |= 0x8000;
    }
    __syncthreads();

    // --- compaction: selected ascending then unselected ascending (packed) ---
    int cnt = 0;
    for (int l = lo; l < hi; ++l) cnt += (s_pk[l] & 0x8000) ? 1 : 0x10000;
    const int pb = block_exscan_fast(cnt, s_warp, tid);
    const int S = s_warp[15] & 0xFFFF;            // total selected
    int bs = pb & 0xFFFF, bu = (pb >> 16) + S;
    for (int l = lo; l < hi; ++l) {
        if (s_pk[l] & 0x8000) { if (bs < NSAMP) s_idx[bs] = l; ++bs; }
        else                  { if (bu < NSAMP) s_idx[bu] = l; ++bu; }
    }
    __syncthreads();

    // --- gather + write all 4 outputs (ints written as float values) ---
    if (tid < NSAMP) {
        const int l = s_idx[tid];
        float4 bx = (l < NN) ? ((const float4*)(boxes + (size_t)b * NN * 4))[l]
                             : ((const float4*)(gt + (size_t)b * MM * 4))[l - NN];
        const int p = s_pk[l];
        const int c = p & 3, mi = (p >> 2) & 0xFF;
        const bool bg = (c != 1);          // background = matched_val < 0.5
        float4 gb = make_float4(0.f, 0.f, 0.f, 0.f);
        int cl = 0, si = -1;
        if (!bg) {
            gb = ((const float4*)(gt + (size_t)b * MM * 4))[mi];
            cl = gtc[(size_t)b * MM + mi];
            si = mi;
        }
        const size_t rk = (size_t)b * NSAMP + tid;
        ((float4*)out)[rk] = bx;                                   // rois
        ((float4*)(out + (size_t)BB * NSAMP * 4))[rk] = gb;        // sampled_gt_boxes
        out[(size_t)2 * BB * NSAMP * 4 + rk] = (float)cl;          // classes
        out[(size_t)2 * BB * NSAMP * 4 + (size_t)BB * NSAMP + rk] = (float)si; // indices
    }
}

extern "C" void kernel_launch(void* const* d_in, const int* in_sizes, int n_in,
                              void* d_out, int out_size, void* d_ws, size_t ws_size,
                              hipStream_t stream)
{
    const float* boxes = (const float*)d_in[0];   // [32,8000,4] f32
    const float* gt    = (const float*)d_in[1];   // [32,256,4]  f32
    const int*   gtc   = (const int*)  d_in[2];   // [32,256]    i32
    const float* rnd   = (const float*)d_in[3];   // [32,8256]   f32
    float* out = (float*)d_out;
    uint8_t*  pidx   = (uint8_t*)d_ws;                                     // 1.06 MB
    uint16_t* packed = (uint16_t*)((char*)d_ws + (size_t)BB * LL * SPLIT); // 0.53 MB

    dim3 g1((LL + 255) / 256, BB, SPLIT);
    match_split_kernel<<<g1, 256, 0, stream>>>(boxes, gt, pidx);
    dim3 g2((LL + 255) / 256, BB);
    merge_kernel<<<g2, 256, 0, stream>>>(boxes, gt, pidx, packed);
    sample_kernel<<<BB, T2, 0, stream>>>(boxes, gt, gtc, rnd, packed, out);
}